// Round 18
// baseline (191.498 us; speedup 1.0000x reference)
//
#include <hip/hip_runtime.h>
#include <stdint.h>

#define NA 98304
#define NT 1024
#define NC 21
#define ACH 192          // anchor chunks of 512 sorted ranks (2 per thread)
#define TCH 8            // target chunks of 128 sorted ranks
#define NBLK (ACH * TCH) // 1536
#define HI_MIN 0xBF000000u   // min high-word of a valid key (iou>=0.5, bias bit)
#define POISON 0xAAAAAAAAu   // harness re-poisons ws to 0xAA before EVERY launch

// ws layout (NO memset — everything poison-tolerant or overwritten pre-use):
//   [0]      uint g_ahist[256]   (POISON-offset anchor histogram)
//   [1024]   uint g_acur[256]    (scatter cursors, written by k_scan)
//   [2048]   int  t_off[257]     (target bucket prefix, written by k_sort1)
//   [3584]   uint done2          (counts up from POISON)
//   [3648]   uint done_ac[192]
//   [4608]   float f0_part[1536] (unique-slot stores)
//   [10752]  float corr_part[192]
//   [11520]  int   npos_part[192]
//   [12288]  u64   tkeys[NT]     (poison-proof keys)
//   [20480]  int   st_orig[1024]
//   [24576]  u64   akeys[NA]     (poison-proof keys)
//   [811008] float4 st_box[1024]
//   [827392] int  sa_orig[NA]    -> end ~1.22 MB

__device__ __forceinline__ float f0(float x) {   // focal, target=0
    const float ax = fabsf(x);
    const float u  = __expf(-ax);
    const float ce = fmaxf(x, 0.f) + __logf(1.f + u);
    const float p  = (x >= 0.f ? 1.f : u) / (1.f + u);
    return 0.75f * p * p * ce;
}
__device__ __forceinline__ float f1(float x) {   // focal, target=1
    const float ax = fabsf(x);
    const float u  = __expf(-ax);
    const float ce = fmaxf(x, 0.f) - x + __logf(1.f + u);
    const float p  = (x >= 0.f ? 1.f : u) / (1.f + u);
    const float q  = 1.f - p;
    return 0.25f * q * q * ce;
}
__device__ __forceinline__ unsigned long long mk_key(float iou, unsigned int idx) {
    return ((unsigned long long)(__float_as_uint(iou) | 0x80000000u) << 32) |
           (unsigned long long)(0xFFFFFFFFu - idx);
}
__device__ __forceinline__ float smooth_l1(float d) {
    const float ad = fabsf(d);
    return (ad < 1.f) ? 0.5f * d * d : ad - 0.5f;
}
__device__ __forceinline__ unsigned long long aload64(const unsigned long long* p) {
    return __hip_atomic_load(p, __ATOMIC_RELAXED, __HIP_MEMORY_SCOPE_AGENT);
}
__device__ __forceinline__ float aloadf(const float* p) {
    return __hip_atomic_load(p, __ATOMIC_RELAXED, __HIP_MEMORY_SCOPE_AGENT);
}
__device__ __forceinline__ int aloadi(const int* p) {
    return __hip_atomic_load(p, __ATOMIC_RELAXED, __HIP_MEMORY_SCOPE_AGENT);
}
__device__ __forceinline__ int buck(float cx) {   // monotone cx -> bucket
    const int b = (int)((cx - 0.15f) * (256.0f / 0.7f));
    return min(max(b, 0), 255);
}

// ==== K1: block 384 sorts targets by cx; blocks 0..383 histogram anchors ====
__global__ __launch_bounds__(256) void k_sort1(
    const float4* __restrict__ anchors, const float4* __restrict__ tboxes,
    unsigned* __restrict__ g_ahist, int* __restrict__ t_off,
    float4* __restrict__ st_box, int* __restrict__ st_orig)
{
    const int tid = threadIdx.x;
    if (blockIdx.x == 384) {
        __shared__ int h[256], cur[256];
        h[tid] = 0;
        __syncthreads();
        float4 tb[4]; int bb[4];
        #pragma unroll
        for (int j = 0; j < 4; ++j) {
            tb[j] = tboxes[tid + j * 256];
            bb[j] = buck(0.5f * (tb[j].x + tb[j].z));
            atomicAdd(&h[bb[j]], 1);
        }
        __syncthreads();
        if (tid == 0) {
            int s = 0;
            for (int i = 0; i < 256; ++i) { cur[i] = s; t_off[i] = s; s += h[i]; }
            t_off[256] = s;
        }
        __syncthreads();
        #pragma unroll
        for (int j = 0; j < 4; ++j) {
            const int pos = atomicAdd(&cur[bb[j]], 1);
            st_box[pos]  = tb[j];
            st_orig[pos] = tid + j * 256;
        }
    } else {
        __shared__ int h[256];
        h[tid] = 0;
        __syncthreads();
        const float4 ab = anchors[blockIdx.x * 256 + tid];
        atomicAdd(&h[buck(0.5f * (ab.x + ab.z))], 1);
        __syncthreads();
        if (h[tid]) atomicAdd(&g_ahist[tid], (unsigned)h[tid]);  // POISON-offset
    }
}

// ==== K2: exclusive scan of anchor histogram -> scatter cursors ====
__global__ __launch_bounds__(256) void k_scan(
    const unsigned* __restrict__ g_ahist, unsigned* __restrict__ g_acur)
{
    __shared__ unsigned v[256];
    const int tid = threadIdx.x;
    const unsigned cnt = g_ahist[tid] - POISON;
    v[tid] = cnt;
    __syncthreads();
    for (int off = 1; off < 256; off <<= 1) {
        const unsigned x = (tid >= off) ? v[tid - off] : 0u;
        __syncthreads();
        v[tid] += x;
        __syncthreads();
    }
    g_acur[tid] = v[tid] - cnt;   // exclusive prefix
}

// ==== K3: scatter anchors into cx-sorted rank order (original ids) ====
__global__ __launch_bounds__(256) void k_scat(
    const float4* __restrict__ anchors, unsigned* __restrict__ g_acur,
    int* __restrict__ sa_orig)
{
    const int a = blockIdx.x * 256 + threadIdx.x;
    const float4 ab = anchors[a];
    const unsigned pos = atomicAdd(&g_acur[buck(0.5f * (ab.x + ab.z))], 1u);
    sa_orig[pos] = a;
}

// ==== K4: windowed match + f0 + fused epilogue ====
__global__ __launch_bounds__(256) void k_all(
    const float* __restrict__ preds,
    const float4* __restrict__ preds4,
    const int* __restrict__ tlabels,
    const float4* __restrict__ anchors,
    const float4* __restrict__ tboxes,
    const float4* __restrict__ bpreds,
    const int* __restrict__ sa_orig,
    const float4* __restrict__ st_box,
    const int* __restrict__ st_orig,
    const int* __restrict__ t_off,
    unsigned long long* __restrict__ akeys,
    unsigned long long* __restrict__ tkeys,
    float* __restrict__ f0_part,
    float* __restrict__ corr_part,
    int* __restrict__ npos_part,
    unsigned* __restrict__ done_ac,
    unsigned* __restrict__ done2,
    float* __restrict__ out)
{
    __shared__ float4 s_t[128];
    __shared__ int    s_to[128];
    __shared__ unsigned long long s_tk[128];
    __shared__ float s_f[4];
    __shared__ int   s_last, s_fin;
    __shared__ float s_a[4];
    __shared__ int   s_c[4];
    __shared__ double s_d[4];
    __shared__ int    s_i[4];
    __shared__ float  s_s[4], s_m[4];

    const int tid   = threadIdx.x;
    const int ac    = blockIdx.x;
    const int L     = blockIdx.y * ACH + ac;
    const int tbase = blockIdx.y * 128;
    const int lane  = tid & 63, wid = tid >> 6;

    // ================= PHASE A: windowed match + f0 slice =====================
    if (tid < 128) {
        s_t[tid]  = st_box[tbase + tid];
        s_to[tid] = st_orig[tbase + tid];
        s_tk[tid] = 0ull;
    }
    const unsigned oa0 = (unsigned)sa_orig[ac * 512 + tid];         // coalesced
    const unsigned oa1 = (unsigned)sa_orig[ac * 512 + tid + 256];
    const float4 A0 = anchors[oa0];   // gather, L2/L3-backed
    const float4 A1 = anchors[oa1];

    // f0 over this block's contiguous 336-float4 slice of preds (no match dep)
    float facc;
    {
        const int pb = L * 336;
        const float4 v0 = preds4[pb + tid];
        facc = (f0(v0.x) + f0(v0.y)) + (f0(v0.z) + f0(v0.w));
        if (tid < 80) {
            const float4 v1 = preds4[pb + 256 + tid];
            facc += (f0(v1.x) + f0(v1.y)) + (f0(v1.z) + f0(v1.w));
        }
    }
    __syncthreads();

    const float ar0 = (A0.z - A0.x) * (A0.w - A0.y);
    const float ar1 = (A1.z - A1.x) * (A1.w - A1.y);

    // x-window: iou>=0.5 requires |acx-tcx| <= min(aw,tw)/2 <= aw/2, i.e.
    // tcx within the anchor's own x-extent. Wave-union -> uniform bounds.
    float wlo, whi;
    {
        wlo = fminf(A0.x, A1.x) - 2e-3f;
        whi = fmaxf(A0.z, A1.z) + 2e-3f;
        #pragma unroll
        for (int o = 1; o < 64; o <<= 1) {
            wlo = fminf(wlo, __shfl_xor(wlo, o));
            whi = fmaxf(whi, __shfl_xor(whi, o));
        }
    }
    const int ilo = max(t_off[buck(wlo)], tbase);
    const int ihi = min(t_off[buck(whi) + 1], tbase + 128);

    float b0 = 0.f, b1 = 0.f;
    unsigned o0 = 0xFFFFFFFFu, o1 = 0xFFFFFFFFu;

    #pragma unroll 4
    for (int t = ilo - tbase; t < ihi - tbase; ++t) {
        const float4 tb = s_t[t];          // broadcast b128, shared by 2 anchors
        const float sa = (tb.z - tb.x) * (tb.w - tb.y);
        {
            const float w  = fmaxf(fminf(A0.z, tb.z) - fmaxf(A0.x, tb.x), 0.f);
            const float h  = fmaxf(fminf(A0.w, tb.w) - fmaxf(A0.y, tb.y), 0.f);
            const float inter = w * h;
            const float uni = (ar0 + sa) - inter;
            if (__builtin_expect(inter + inter >= uni, 0)) {
                const float iou = inter / uni;   // exact div = reference rounding
                const unsigned to = (unsigned)s_to[t];
                if (iou > b0 || (iou == b0 && to < o0)) { b0 = iou; o0 = to; }
                atomicMax(&s_tk[t], mk_key(iou, oa0));
            }
        }
        {
            const float w  = fmaxf(fminf(A1.z, tb.z) - fmaxf(A1.x, tb.x), 0.f);
            const float h  = fmaxf(fminf(A1.w, tb.w) - fmaxf(A1.y, tb.y), 0.f);
            const float inter = w * h;
            const float uni = (ar1 + sa) - inter;
            if (__builtin_expect(inter + inter >= uni, 0)) {
                const float iou = inter / uni;
                const unsigned to = (unsigned)s_to[t];
                if (iou > b1 || (iou == b1 && to < o1)) { b1 = iou; o1 = to; }
                atomicMax(&s_tk[t], mk_key(iou, oa1));
            }
        }
    }

    // fire-and-forget flushes, ORIGINAL indices (tie-break via key low word)
    if (o0 != 0xFFFFFFFFu) atomicMax(&akeys[oa0], mk_key(b0, o0));
    if (o1 != 0xFFFFFFFFu) atomicMax(&akeys[oa1], mk_key(b1, o1));

    for (int o = 32; o > 0; o >>= 1) facc += __shfl_down(facc, o);
    if (lane == 0) s_f[wid] = facc;

    __syncthreads();
    if (tid < 128) {
        const unsigned long long tk = s_tk[tid];
        if (tk != 0ull) atomicMax(&tkeys[s_to[tid]], tk);
    }
    if (tid == 0)
        __hip_atomic_store(&f0_part[L], s_f[0] + s_f[1] + s_f[2] + s_f[3],
                           __ATOMIC_RELAXED, __HIP_MEMORY_SCOPE_AGENT);

    __syncthreads();   // drains vmcnt: key flushes complete before counter bump
    if (tid == 0) {
        __threadfence();
        s_last = (atomicAdd(&done_ac[ac], 1u) == POISON + TCH - 1);
    }
    __syncthreads();
    if (!s_last) return;
    __builtin_amdgcn_fence(__ATOMIC_ACQUIRE, "agent");

    // ============ PHASE B (192 completers): corrections over the RANK partition
    // R17 BUG FIX: done_ac[ac] certifies flushes for the anchors of rank-column
    // ac — original ids oa0/oa1 (already in registers) — NOT ids ac*512+tid.
    // Each anchor occupies exactly one rank slot, so this partition is exact.
    float acc = 0.f;
    int   cnt = 0;
    {
        const unsigned long long k = aload64(&akeys[oa0]);
        if ((unsigned int)(k >> 32) >= HI_MIN) {
            cnt = 1;
            const int lab = tlabels[0xFFFFFFFFu - (unsigned int)k];
            const float x = preds[oa0 * NC + lab];
            acc += f1(x) - f0(x);
        }
    }
    {
        const unsigned long long k = aload64(&akeys[oa1]);
        if ((unsigned int)(k >> 32) >= HI_MIN) {
            cnt += 1;
            const int lab = tlabels[0xFFFFFFFFu - (unsigned int)k];
            const float x = preds[oa1 * NC + lab];
            acc += f1(x) - f0(x);
        }
    }
    if (tid < TCH) acc += aloadf(&f0_part[ac + tid * ACH]);

    for (int o = 32; o > 0; o >>= 1) {
        acc += __shfl_down(acc, o);
        cnt += __shfl_down(cnt, o);
    }
    if (lane == 0) { s_a[wid] = acc; s_c[wid] = cnt; }
    __syncthreads();
    if (tid == 0) {
        __hip_atomic_store(&corr_part[ac], s_a[0] + s_a[1] + s_a[2] + s_a[3],
                           __ATOMIC_RELAXED, __HIP_MEMORY_SCOPE_AGENT);
        __hip_atomic_store(&npos_part[ac], s_c[0] + s_c[1] + s_c[2] + s_c[3],
                           __ATOMIC_RELAXED, __HIP_MEMORY_SCOPE_AGENT);
        __threadfence();
        s_fin = (atomicAdd(done2, 1u) == POISON + ACH - 1);
    }
    __syncthreads();
    if (!s_fin) return;
    __builtin_amdgcn_fence(__ATOMIC_ACQUIRE, "agent");

    // ============ PHASE C (last completer): regression + combine ==============
    double cl = 0.0;
    int    np = 0;
    if (tid < ACH) {
        cl = (double)aloadf(&corr_part[tid]);
        np = aloadi(&npos_part[tid]);
    }
    float s = 0.f, m = 0.f;
    #pragma unroll
    for (int j = 0; j < 4; ++j) {
        const int t = tid + 256 * j;
        const unsigned long long key = aload64(&tkeys[t]);
        if ((unsigned int)(key >> 32) >= HI_MIN) {
            const unsigned int ga = 0xFFFFFFFFu - (unsigned int)key;
            const float4 tb  = tboxes[t];
            const float4 abx = anchors[ga];
            const float4 pb  = bpreds[ga];
            const float bw = tb.z - tb.x, bh = tb.w - tb.y;
            const float bcx = tb.x + 0.5f * bw, bcy = tb.y + 0.5f * bh;
            const float aw = abx.z - abx.x, ah = abx.w - abx.y;
            const float acx = abx.x + 0.5f * aw, acy = abx.y + 0.5f * ah;
            const float tx = (bcx - acx) / aw;
            const float ty = (bcy - acy) / ah;
            const float tw = logf(fmaxf(bw, 1e-8f) / aw);
            const float th = logf(fmaxf(bh, 1e-8f) / ah);
            s += smooth_l1(pb.x - tx) + smooth_l1(pb.y - ty) +
                 smooth_l1(pb.z - tw) + smooth_l1(pb.w - th);
            m += 1.f;
        }
    }
    for (int o = 32; o > 0; o >>= 1) {
        cl += __shfl_down(cl, o);
        np += __shfl_down(np, o);
        s  += __shfl_down(s, o);
        m  += __shfl_down(m, o);
    }
    __syncthreads();
    if (lane == 0) { s_d[wid] = cl; s_i[wid] = np; s_s[wid] = s; s_m[wid] = m; }
    __syncthreads();
    if (tid == 0) {
        const double cls_sum = s_d[0] + s_d[1] + s_d[2] + s_d[3];
        const int    npos    = s_i[0] + s_i[1] + s_i[2] + s_i[3];
        const float  rs      = s_s[0] + s_s[1] + s_s[2] + s_s[3];
        const float  rm      = s_m[0] + s_m[1] + s_m[2] + s_m[3];
        const float cls = (float)(cls_sum / (double)npos);
        const float reg = rs / (fmaxf(rm, 1.f) * 4.f);
        out[0] = cls + reg;
        out[1] = cls;
        out[2] = reg;
    }
}

extern "C" void kernel_launch(void* const* d_in, const int* in_sizes, int n_in,
                              void* d_out, int out_size, void* d_ws, size_t ws_size,
                              hipStream_t stream) {
    const float*  preds   = (const float*)d_in[0];
    const float4* preds4  = (const float4*)d_in[0];
    const float4* bpreds  = (const float4*)d_in[1];
    const float4* anchors = (const float4*)d_in[2];
    const float4* tboxes  = (const float4*)d_in[3];
    const int*    tlabels = (const int*)d_in[4];

    char* ws = (char*)d_ws;
    unsigned* g_ahist   = (unsigned*)(ws + 0);
    unsigned* g_acur    = (unsigned*)(ws + 1024);
    int*      t_off     = (int*)(ws + 2048);
    unsigned* done2     = (unsigned*)(ws + 3584);
    unsigned* done_ac   = (unsigned*)(ws + 3648);
    float*    f0_part   = (float*)(ws + 4608);
    float*    corr_part = (float*)(ws + 10752);
    int*      npos_part = (int*)(ws + 11520);
    unsigned long long* tkeys = (unsigned long long*)(ws + 12288);
    int*      st_orig   = (int*)(ws + 20480);
    unsigned long long* akeys = (unsigned long long*)(ws + 24576);
    float4*   st_box    = (float4*)(ws + 811008);
    int*      sa_orig   = (int*)(ws + 827392);

    k_sort1<<<385, 256, 0, stream>>>(anchors, tboxes, g_ahist, t_off,
                                     st_box, st_orig);
    k_scan<<<1, 256, 0, stream>>>(g_ahist, g_acur);
    k_scat<<<384, 256, 0, stream>>>(anchors, g_acur, sa_orig);
    k_all<<<dim3(ACH, TCH), 256, 0, stream>>>(
        preds, preds4, tlabels, anchors, tboxes, bpreds,
        sa_orig, st_box, st_orig, t_off,
        akeys, tkeys, f0_part, corr_part, npos_part,
        done_ac, done2, (float*)d_out);
}

// Round 19
// 153.825 us; speedup vs baseline: 1.2449x; 1.2449x over previous
//
#include <hip/hip_runtime.h>
#include <stdint.h>

#define NA 98304
#define NT 1024
#define NC 21
#define ACH 96           // anchor chunks of 1024 (4 anchors per thread)
#define TCH 8            // target chunks of 128
#define NBLK (ACH * TCH) // 768
#define HI_MIN 0xBF000000u   // min high-word of a valid key (iou>=0.5, bias bit)
#define POISON 0xAAAAAAAAu   // harness re-poisons ws to 0xAA before EVERY launch

// ws layout (NO memset node — everything poison-tolerant):
//   [0]     uint  done2               (counts up from POISON)
//   [64]    uint  done_ac[96]         (count up from POISON)
//   [1024]  float f0_part[NBLK]       (unique-slot stores)
//   [4096]  float corr_part[96]       (unique-slot)
//   [4608]  int   npos_part[96]       (unique-slot)
//   [12288] u64   tkeys[NT]           (poison-proof keys)
//   [24576] u64   akeys[NA]           (poison-proof keys)

__device__ __forceinline__ float f0(float x) {   // focal, target=0
    const float ax = fabsf(x);
    const float u  = __expf(-ax);
    const float ce = fmaxf(x, 0.f) + __logf(1.f + u);
    const float p  = (x >= 0.f ? 1.f : u) / (1.f + u);
    return 0.75f * p * p * ce;
}
__device__ __forceinline__ float f1(float x) {   // focal, target=1
    const float ax = fabsf(x);
    const float u  = __expf(-ax);
    const float ce = fmaxf(x, 0.f) - x + __logf(1.f + u);
    const float p  = (x >= 0.f ? 1.f : u) / (1.f + u);
    const float q  = 1.f - p;
    return 0.25f * q * q * ce;
}
__device__ __forceinline__ unsigned long long mk_key(float iou, unsigned int idx) {
    // bias bit: valid keys beat 0xAA-poison and 0 under unsigned atomicMax;
    // iou ordering preserved; low word 0xFFFFFFFF-idx -> smaller index wins ties.
    return ((unsigned long long)(__float_as_uint(iou) | 0x80000000u) << 32) |
           (unsigned long long)(0xFFFFFFFFu - idx);
}
__device__ __forceinline__ float smooth_l1(float d) {
    const float ad = fabsf(d);
    return (ad < 1.f) ? 0.5f * d * d : ad - 0.5f;
}
__device__ __forceinline__ unsigned long long aload64(const unsigned long long* p) {
    return __hip_atomic_load(p, __ATOMIC_RELAXED, __HIP_MEMORY_SCOPE_AGENT);
}
__device__ __forceinline__ float aloadf(const float* p) {
    return __hip_atomic_load(p, __ATOMIC_RELAXED, __HIP_MEMORY_SCOPE_AGENT);
}
__device__ __forceinline__ int aloadi(const int* p) {
    return __hip_atomic_load(p, __ATOMIC_RELAXED, __HIP_MEMORY_SCOPE_AGENT);
}
__device__ __forceinline__ void iou_iu(const float4 A, const float arA,
                                       const float4 tb, const float sa,
                                       float& inter, float& uni)
{
    const float w = fmaxf(fminf(A.z, tb.z) - fmaxf(A.x, tb.x), 0.f);
    const float h = fmaxf(fminf(A.w, tb.w) - fmaxf(A.y, tb.y), 0.f);
    inter = w * h;
    uni   = (arA + sa) - inter;
}

__global__ __launch_bounds__(256) void k_all(
    const float* __restrict__ preds,
    const float4* __restrict__ preds4,
    const int* __restrict__ tlabels,
    const float4* __restrict__ anchors,
    const float4* __restrict__ tboxes,
    const float4* __restrict__ bpreds,
    unsigned long long* __restrict__ akeys,
    unsigned long long* __restrict__ tkeys,
    float* __restrict__ f0_part,
    float* __restrict__ corr_part,
    int* __restrict__ npos_part,
    unsigned* __restrict__ done_ac,
    unsigned* __restrict__ done2,
    float* __restrict__ out)
{
    __shared__ float4 s_t[128];
    __shared__ unsigned long long s_tk[128];
    __shared__ float s_f[4];
    __shared__ int   s_last, s_fin;
    __shared__ float s_a[4];
    __shared__ int   s_c[4];
    __shared__ double s_d[4];
    __shared__ int    s_i[4];
    __shared__ float  s_s[4], s_m[4];

    const int tid   = threadIdx.x;
    const int ac    = blockIdx.x;
    const int L     = blockIdx.y * ACH + ac;
    const int tbase = blockIdx.y * 128;
    const int a0    = ac * 1024 + tid;   // anchors a0, +256, +512, +768
    const int lane  = tid & 63, wid = tid >> 6;

    // ================= PHASE A: match (R7 geometry) + f0 slice ================
    if (tid < 128) {
        s_t[tid]  = tboxes[tbase + tid];
        s_tk[tid] = 0ull;
    }
    const float4 A0 = anchors[a0];
    const float4 A1 = anchors[a0 + 256];
    const float4 A2 = anchors[a0 + 512];
    const float4 A3 = anchors[a0 + 768];

    // f0 over this block's contiguous 672-float4 slice of preds (no match dep)
    float facc;
    {
        const int pb = L * 672;
        const float4 v0 = preds4[pb + tid];
        const float4 v1 = preds4[pb + 256 + tid];
        facc  = (f0(v0.x) + f0(v0.y)) + (f0(v0.z) + f0(v0.w));
        facc += (f0(v1.x) + f0(v1.y)) + (f0(v1.z) + f0(v1.w));
        if (tid < 160) {
            const float4 v2 = preds4[pb + 512 + tid];
            facc += (f0(v2.x) + f0(v2.y)) + (f0(v2.z) + f0(v2.w));
        }
    }
    __syncthreads();

    const float ar0 = (A0.z - A0.x) * (A0.w - A0.y);
    const float ar1 = (A1.z - A1.x) * (A1.w - A1.y);
    const float ar2 = (A2.z - A2.x) * (A2.w - A2.y);
    const float ar3 = (A3.z - A3.x) * (A3.w - A3.y);

    float b0 = 0.f, b1 = 0.f, b2 = 0.f, b3 = 0.f;
    int   i0 = -1,  i1 = -1,  i2 = -1,  i3 = -1;

    #pragma unroll 4
    for (int t = 0; t < 128; ++t) {
        const float4 tb = s_t[t];          // one broadcast b128 feeds 4 anchors
        const float sa = (tb.z - tb.x) * (tb.w - tb.y);

        float in0, un0, in1, un1, in2, un2, in3, un3;
        iou_iu(A0, ar0, tb, sa, in0, un0);
        iou_iu(A1, ar1, tb, sa, in1, un1);
        iou_iu(A2, ar2, tb, sa, in2, un2);
        iou_iu(A3, ar3, tb, sa, in3, un3);

        const bool h0 = (in0 + in0 >= un0);
        const bool h1 = (in1 + in1 >= un1);
        const bool h2 = (in2 + in2 >= un2);
        const bool h3 = (in3 + in3 >= un3);

        // ONE branch per iteration for all 4 anchors (R7-proven)
        if (__builtin_expect((h0 | h1) | (h2 | h3), 0)) {
            if (h0) { const float iou = in0 / un0;
                if (iou > b0) { b0 = iou; i0 = t; }
                atomicMax(&s_tk[t], mk_key(iou, (unsigned int)a0)); }
            if (h1) { const float iou = in1 / un1;
                if (iou > b1) { b1 = iou; i1 = t; }
                atomicMax(&s_tk[t], mk_key(iou, (unsigned int)(a0 + 256))); }
            if (h2) { const float iou = in2 / un2;
                if (iou > b2) { b2 = iou; i2 = t; }
                atomicMax(&s_tk[t], mk_key(iou, (unsigned int)(a0 + 512))); }
            if (h3) { const float iou = in3 / un3;
                if (iou > b3) { b3 = iou; i3 = t; }
                atomicMax(&s_tk[t], mk_key(iou, (unsigned int)(a0 + 768))); }
        }
    }

    // fire-and-forget flushes ONLY (no return-value dependence — R9 lesson)
    if (i0 >= 0) atomicMax(&akeys[a0],       mk_key(b0, (unsigned int)(tbase + i0)));
    if (i1 >= 0) atomicMax(&akeys[a0 + 256], mk_key(b1, (unsigned int)(tbase + i1)));
    if (i2 >= 0) atomicMax(&akeys[a0 + 512], mk_key(b2, (unsigned int)(tbase + i2)));
    if (i3 >= 0) atomicMax(&akeys[a0 + 768], mk_key(b3, (unsigned int)(tbase + i3)));

    for (int o = 32; o > 0; o >>= 1) facc += __shfl_down(facc, o);
    if (lane == 0) s_f[wid] = facc;

    __syncthreads();
    if (tid < 128) {
        const unsigned long long tk = s_tk[tid];
        if (tk != 0ull) atomicMax(&tkeys[tbase + tid], tk);
    }
    if (tid == 0)   // unique slot, agent-scope store
        __hip_atomic_store(&f0_part[L], s_f[0] + s_f[1] + s_f[2] + s_f[3],
                           __ATOMIC_RELAXED, __HIP_MEMORY_SCOPE_AGENT);

    // barrier drains vmcnt: this block's key flushes complete before counter bump
    __syncthreads();
    if (tid == 0) {
        __threadfence();
        s_last = (atomicAdd(&done_ac[ac], 1u) == POISON + TCH - 1);
    }
    __syncthreads();
    if (!s_last) return;
    __builtin_amdgcn_fence(__ATOMIC_ACQUIRE, "agent");   // L1 invalidate

    // ============ PHASE B (96 completers): corrections for 1024 anchors =======
    float acc = 0.f;
    int   cnt = 0;
    #pragma unroll
    for (int j = 0; j < 4; ++j) {
        const int a = a0 + j * 256;
        const unsigned long long k = aload64(&akeys[a]);
        if ((unsigned int)(k >> 32) >= HI_MIN) {
            cnt += 1;
            const int lab = tlabels[0xFFFFFFFFu - (unsigned int)k];
            const float x = preds[a * NC + lab];
            acc += f1(x) - f0(x);
        }
    }
    // fold the 8 f0 slices of this ac (written + fenced before done_ac bumps)
    if (tid < TCH) acc += aloadf(&f0_part[ac + tid * ACH]);

    for (int o = 32; o > 0; o >>= 1) {
        acc += __shfl_down(acc, o);
        cnt += __shfl_down(cnt, o);
    }
    if (lane == 0) { s_a[wid] = acc; s_c[wid] = cnt; }
    __syncthreads();
    if (tid == 0) {
        __hip_atomic_store(&corr_part[ac], s_a[0] + s_a[1] + s_a[2] + s_a[3],
                           __ATOMIC_RELAXED, __HIP_MEMORY_SCOPE_AGENT);
        __hip_atomic_store(&npos_part[ac], s_c[0] + s_c[1] + s_c[2] + s_c[3],
                           __ATOMIC_RELAXED, __HIP_MEMORY_SCOPE_AGENT);
        __threadfence();
        s_fin = (atomicAdd(done2, 1u) == POISON + ACH - 1);
    }
    __syncthreads();
    if (!s_fin) return;
    __builtin_amdgcn_fence(__ATOMIC_ACQUIRE, "agent");

    // ============ PHASE C (last completer): regression + combine ==============
    double cl = 0.0;
    int    np = 0;
    if (tid < ACH) {
        cl = (double)aloadf(&corr_part[tid]);
        np = aloadi(&npos_part[tid]);
    }
    float s = 0.f, m = 0.f;
    #pragma unroll
    for (int j = 0; j < 4; ++j) {
        const int t = tid + 256 * j;
        const unsigned long long key = aload64(&tkeys[t]);
        if ((unsigned int)(key >> 32) >= HI_MIN) {
            const unsigned int ga = 0xFFFFFFFFu - (unsigned int)key;
            const float4 tb  = tboxes[t];
            const float4 abx = anchors[ga];
            const float4 pb  = bpreds[ga];
            const float bw = tb.z - tb.x, bh = tb.w - tb.y;
            const float bcx = tb.x + 0.5f * bw, bcy = tb.y + 0.5f * bh;
            const float aw = abx.z - abx.x, ah = abx.w - abx.y;
            const float acx = abx.x + 0.5f * aw, acy = abx.y + 0.5f * ah;
            const float tx = (bcx - acx) / aw;
            const float ty = (bcy - acy) / ah;
            const float tw = logf(fmaxf(bw, 1e-8f) / aw);
            const float th = logf(fmaxf(bh, 1e-8f) / ah);
            s += smooth_l1(pb.x - tx) + smooth_l1(pb.y - ty) +
                 smooth_l1(pb.z - tw) + smooth_l1(pb.w - th);
            m += 1.f;
        }
    }
    for (int o = 32; o > 0; o >>= 1) {
        cl += __shfl_down(cl, o);
        np += __shfl_down(np, o);
        s  += __shfl_down(s, o);
        m  += __shfl_down(m, o);
    }
    __syncthreads();
    if (lane == 0) { s_d[wid] = cl; s_i[wid] = np; s_s[wid] = s; s_m[wid] = m; }
    __syncthreads();
    if (tid == 0) {
        const double cls_sum = s_d[0] + s_d[1] + s_d[2] + s_d[3];
        const int    npos    = s_i[0] + s_i[1] + s_i[2] + s_i[3];
        const float  rs      = s_s[0] + s_s[1] + s_s[2] + s_s[3];
        const float  rm      = s_m[0] + s_m[1] + s_m[2] + s_m[3];
        const float cls = (float)(cls_sum / (double)npos);
        const float reg = rs / (fmaxf(rm, 1.f) * 4.f);
        out[0] = cls + reg;
        out[1] = cls;
        out[2] = reg;
    }
}

extern "C" void kernel_launch(void* const* d_in, const int* in_sizes, int n_in,
                              void* d_out, int out_size, void* d_ws, size_t ws_size,
                              hipStream_t stream) {
    const float*  preds   = (const float*)d_in[0];
    const float4* preds4  = (const float4*)d_in[0];
    const float4* bpreds  = (const float4*)d_in[1];
    const float4* anchors = (const float4*)d_in[2];
    const float4* tboxes  = (const float4*)d_in[3];
    const int*    tlabels = (const int*)d_in[4];

    char* ws = (char*)d_ws;
    unsigned* done2     = (unsigned*)(ws + 0);
    unsigned* done_ac   = (unsigned*)(ws + 64);
    float*    f0_part   = (float*)(ws + 1024);
    float*    corr_part = (float*)(ws + 4096);
    int*      npos_part = (int*)(ws + 4608);
    unsigned long long* tkeys = (unsigned long long*)(ws + 12288);
    unsigned long long* akeys = (unsigned long long*)(ws + 24576);

    // NO memset: done counters count up from the 0xAA poison value,
    // keys are poison-proof, partial slots are unique-slot overwritten.
    k_all<<<dim3(ACH, TCH), 256, 0, stream>>>(
        preds, preds4, tlabels, anchors, tboxes, bpreds,
        akeys, tkeys, f0_part, corr_part, npos_part,
        done_ac, done2, (float*)d_out);
}

// Round 20
// 138.269 us; speedup vs baseline: 1.3850x; 1.1125x over previous
//
#include <hip/hip_runtime.h>
#include <stdint.h>

#define NA 98304
#define NT 1024
#define NC 21
#define ACH 192          // anchor chunks of 512 (2 anchors per thread)
#define TCH 8            // target chunks of 128
#define NBLK (ACH * TCH) // 1536
#define HI_MIN 0xBF000000u   // min high-word of a valid key (iou>=0.5, bias bit)

// ws layout:
//   [0]     int   done2                 (zeroed by memset)
//   [64]    int   done_ac[192]          (768 B, zeroed by memset)
//   [1024]  float f0_part[NBLK]         (6 KB, unique-slot atomicExch)
//   [7168]  float corr_part[192]        (768 B, unique-slot atomicExch)
//   [7936]  int   npos_part[192]        (768 B, unique-slot atomicExch)
//   [12288] u64   tkeys[NT]             (8 KB, NOT zeroed: poison-proof keys)
//   [20480] u64   akeys[NA]             (768 KB, NOT zeroed)
// memset covers only [0, 1024)

__device__ __forceinline__ float f0(float x) {   // focal, target=0
    const float ax = fabsf(x);
    const float u  = __expf(-ax);
    const float ce = fmaxf(x, 0.f) + __logf(1.f + u);
    const float p  = (x >= 0.f ? 1.f : u) / (1.f + u);
    return 0.75f * p * p * ce;
}
__device__ __forceinline__ float f1(float x) {   // focal, target=1
    const float ax = fabsf(x);
    const float u  = __expf(-ax);
    const float ce = fmaxf(x, 0.f) - x + __logf(1.f + u);
    const float p  = (x >= 0.f ? 1.f : u) / (1.f + u);
    const float q  = 1.f - p;
    return 0.25f * q * q * ce;
}
__device__ __forceinline__ unsigned long long mk_key(float iou, unsigned int idx) {
    // bias bit: valid keys beat 0xAA-poison and 0 under unsigned atomicMax;
    // iou ordering preserved; low word 0xFFFFFFFF-idx -> smaller index wins ties.
    return ((unsigned long long)(__float_as_uint(iou) | 0x80000000u) << 32) |
           (unsigned long long)(0xFFFFFFFFu - idx);
}
__device__ __forceinline__ float smooth_l1(float d) {
    const float ad = fabsf(d);
    return (ad < 1.f) ? 0.5f * d * d : ad - 0.5f;
}

__global__ __launch_bounds__(256) void k_all(
    const float* __restrict__ preds,
    const float4* __restrict__ preds4,
    const int* __restrict__ tlabels,
    const float4* __restrict__ anchors,
    const float4* __restrict__ tboxes,
    const float4* __restrict__ bpreds,
    unsigned long long* __restrict__ akeys,
    unsigned long long* __restrict__ tkeys,
    float* __restrict__ f0_part,
    float* __restrict__ corr_part,
    int* __restrict__ npos_part,
    int* __restrict__ done_ac,
    int* __restrict__ done2,
    float* __restrict__ out)
{
    __shared__ float4 s_t[128];
    __shared__ unsigned long long s_tk[128];
    __shared__ float s_f[4];
    __shared__ int   s_last, s_fin;
    __shared__ float s_a[4];
    __shared__ int   s_c[4];
    __shared__ double s_d[4];
    __shared__ int    s_i[4];
    __shared__ float  s_s[4], s_m[4];

    const int tid   = threadIdx.x;
    const int ac    = blockIdx.x;
    const int L     = blockIdx.y * ACH + ac;
    const int tbase = blockIdx.y * 128;
    const int a0    = ac * 512 + tid;
    const int a1    = a0 + 256;
    const int lane  = tid & 63, wid = tid >> 6;

    // ================= PHASE A: match (R10/R12-proven) + f0 slice =============
    if (tid < 128) {
        s_t[tid]  = tboxes[tbase + tid];
        s_tk[tid] = 0ull;
    }
    const float4 A0 = anchors[a0];
    const float4 A1 = anchors[a1];

    // f0 over this block's contiguous 336-float4 slice of preds (no match dep)
    float facc;
    {
        const int pb = L * 336;
        const float4 v0 = preds4[pb + tid];
        facc = (f0(v0.x) + f0(v0.y)) + (f0(v0.z) + f0(v0.w));
        if (tid < 80) {
            const float4 v1 = preds4[pb + 256 + tid];
            facc += (f0(v1.x) + f0(v1.y)) + (f0(v1.z) + f0(v1.w));
        }
    }
    __syncthreads();

    const float ar0 = (A0.z - A0.x) * (A0.w - A0.y);
    const float ar1 = (A1.z - A1.x) * (A1.w - A1.y);

    float b0 = 0.f, b1 = 0.f;
    int   i0 = -1,  i1 = -1;

    #pragma unroll 4
    for (int t = 0; t < 128; ++t) {
        const float4 tb = s_t[t];          // one broadcast b128, shared by 2 anchors
        const float sa = (tb.z - tb.x) * (tb.w - tb.y);
        {
            const float lx = fmaxf(A0.x, tb.x);
            const float ly = fmaxf(A0.y, tb.y);
            const float rx = fminf(A0.z, tb.z);
            const float ry = fminf(A0.w, tb.w);
            const float w  = fmaxf(rx - lx, 0.f);
            const float h  = fmaxf(ry - ly, 0.f);
            const float inter = w * h;
            const float uni = (ar0 + sa) - inter;
            if (__builtin_expect(inter + inter >= uni, 0)) {
                const float iou = inter / uni;   // exact div = reference rounding
                if (iou > b0) { b0 = iou; i0 = t; }
                atomicMax(&s_tk[t], mk_key(iou, (unsigned int)a0));
            }
        }
        {
            const float lx = fmaxf(A1.x, tb.x);
            const float ly = fmaxf(A1.y, tb.y);
            const float rx = fminf(A1.z, tb.z);
            const float ry = fminf(A1.w, tb.w);
            const float w  = fmaxf(rx - lx, 0.f);
            const float h  = fmaxf(ry - ly, 0.f);
            const float inter = w * h;
            const float uni = (ar1 + sa) - inter;
            if (__builtin_expect(inter + inter >= uni, 0)) {
                const float iou = inter / uni;
                if (iou > b1) { b1 = iou; i1 = t; }
                atomicMax(&s_tk[t], mk_key(iou, (unsigned int)a1));
            }
        }
    }

    // fire-and-forget flushes ONLY (no return-value dependence — R9 lesson)
    if (i0 >= 0) atomicMax(&akeys[a0], mk_key(b0, (unsigned int)(tbase + i0)));
    if (i1 >= 0) atomicMax(&akeys[a1], mk_key(b1, (unsigned int)(tbase + i1)));

    for (int o = 32; o > 0; o >>= 1) facc += __shfl_down(facc, o);
    if (lane == 0) s_f[wid] = facc;

    __syncthreads();
    if (tid < 128) {
        const unsigned long long tk = s_tk[tid];
        if (tk != 0ull) atomicMax(&tkeys[tbase + tid], tk);
    }
    if (tid == 0)   // unique slot, device-scope atomic store
        atomicExch(&f0_part[L], s_f[0] + s_f[1] + s_f[2] + s_f[3]);

    // barrier drains vmcnt: this block's key flushes complete before counter bump
    __syncthreads();
    if (tid == 0) {
        __threadfence();
        s_last = (atomicAdd(&done_ac[ac], 1) == TCH - 1);
    }
    __syncthreads();
    if (!s_last) return;

    // ============ PHASE B (192 completers): corrections for 512 anchors =======
    float acc = 0.f;
    int   cnt = 0;
    {
        const unsigned long long k = atomicMax(&akeys[a0], 0ull);  // coherent read
        if ((unsigned int)(k >> 32) >= HI_MIN) {
            cnt = 1;
            const int lab = tlabels[0xFFFFFFFFu - (unsigned int)k];
            const float x = preds[a0 * NC + lab];
            acc += f1(x) - f0(x);
        }
    }
    {
        const unsigned long long k = atomicMax(&akeys[a1], 0ull);
        if ((unsigned int)(k >> 32) >= HI_MIN) {
            cnt += 1;
            const int lab = tlabels[0xFFFFFFFFu - (unsigned int)k];
            const float x = preds[a1 * NC + lab];
            acc += f1(x) - f0(x);
        }
    }
    // fold the 8 f0 slices of this ac (written + fenced before done_ac bumps)
    if (tid < TCH) acc += atomicAdd(&f0_part[ac + tid * ACH], 0.f);

    for (int o = 32; o > 0; o >>= 1) {
        acc += __shfl_down(acc, o);
        cnt += __shfl_down(cnt, o);
    }
    if (lane == 0) { s_a[wid] = acc; s_c[wid] = cnt; }
    __syncthreads();
    if (tid == 0) {
        atomicExch(&corr_part[ac], s_a[0] + s_a[1] + s_a[2] + s_a[3]);
        atomicExch(&npos_part[ac], s_c[0] + s_c[1] + s_c[2] + s_c[3]);
        __threadfence();
        s_fin = (atomicAdd(done2, 1) == ACH - 1);
    }
    __syncthreads();
    if (!s_fin) return;

    // ============ PHASE C (last completer): regression + combine ==============
    double cl = 0.0;
    int    np = 0;
    if (tid < ACH) {
        cl = (double)atomicAdd(&corr_part[tid], 0.f);   // coherent reads
        np = atomicAdd(&npos_part[tid], 0);
    }
    float s = 0.f, m = 0.f;
    #pragma unroll
    for (int j = 0; j < 4; ++j) {
        const int t = tid + 256 * j;
        const unsigned long long key = atomicMax(&tkeys[t], 0ull);
        if ((unsigned int)(key >> 32) >= HI_MIN) {
            const unsigned int ga = 0xFFFFFFFFu - (unsigned int)key;
            const float4 tb  = tboxes[t];
            const float4 abx = anchors[ga];
            const float4 pb  = bpreds[ga];
            const float bw = tb.z - tb.x, bh = tb.w - tb.y;
            const float bcx = tb.x + 0.5f * bw, bcy = tb.y + 0.5f * bh;
            const float aw = abx.z - abx.x, ah = abx.w - abx.y;
            const float acx = abx.x + 0.5f * aw, acy = abx.y + 0.5f * ah;
            const float tx = (bcx - acx) / aw;
            const float ty = (bcy - acy) / ah;
            const float tw = logf(fmaxf(bw, 1e-8f) / aw);
            const float th = logf(fmaxf(bh, 1e-8f) / ah);
            s += smooth_l1(pb.x - tx) + smooth_l1(pb.y - ty) +
                 smooth_l1(pb.z - tw) + smooth_l1(pb.w - th);
            m += 1.f;
        }
    }
    for (int o = 32; o > 0; o >>= 1) {
        cl += __shfl_down(cl, o);
        np += __shfl_down(np, o);
        s  += __shfl_down(s, o);
        m  += __shfl_down(m, o);
    }
    __syncthreads();
    if (lane == 0) { s_d[wid] = cl; s_i[wid] = np; s_s[wid] = s; s_m[wid] = m; }
    __syncthreads();
    if (tid == 0) {
        const double cls_sum = s_d[0] + s_d[1] + s_d[2] + s_d[3];
        const int    npos    = s_i[0] + s_i[1] + s_i[2] + s_i[3];
        const float  rs      = s_s[0] + s_s[1] + s_s[2] + s_s[3];
        const float  rm      = s_m[0] + s_m[1] + s_m[2] + s_m[3];
        const float cls = (float)(cls_sum / (double)npos);
        const float reg = rs / (fmaxf(rm, 1.f) * 4.f);
        out[0] = cls + reg;
        out[1] = cls;
        out[2] = reg;
    }
}

extern "C" void kernel_launch(void* const* d_in, const int* in_sizes, int n_in,
                              void* d_out, int out_size, void* d_ws, size_t ws_size,
                              hipStream_t stream) {
    const float*  preds   = (const float*)d_in[0];
    const float4* preds4  = (const float4*)d_in[0];
    const float4* bpreds  = (const float4*)d_in[1];
    const float4* anchors = (const float4*)d_in[2];
    const float4* tboxes  = (const float4*)d_in[3];
    const int*    tlabels = (const int*)d_in[4];

    char* ws = (char*)d_ws;
    int*    done2     = (int*)(ws + 0);
    int*    done_ac   = (int*)(ws + 64);
    float*  f0_part   = (float*)(ws + 1024);
    float*  corr_part = (float*)(ws + 7168);
    int*    npos_part = (int*)(ws + 7936);
    unsigned long long* tkeys = (unsigned long long*)(ws + 12288);
    unsigned long long* akeys = (unsigned long long*)(ws + 20480);

    // only the done counters need zeroing (everything else unique-slot/poison-proof)
    hipMemsetAsync(d_ws, 0, 1024, stream);

    k_all<<<dim3(ACH, TCH), 256, 0, stream>>>(
        preds, preds4, tlabels, anchors, tboxes, bpreds,
        akeys, tkeys, f0_part, corr_part, npos_part,
        done_ac, done2, (float*)d_out);
}